// Round 1
// baseline (781.698 us; speedup 1.0000x reference)
//
#include <hip/hip_runtime.h>

// MoE top-2, D=1024, DFF=4096, E=8, T=4096. Sparse grouped-GEMM, bf16 MFMA,
// global_load_lds staging, pipelined K-half phase schedule (counted vmcnt(6),
// setprio around MFMA cluster), XCD-pinned strip-major schedule.

#define T_TOK 4096
#define DMODEL 1024
#define DFF 4096
#define NE 8
#define CAP 10240           // max aligned slots: 8192 + 8*255 -> 10232, padded
#define MT_CAP 32           // max 256-row m-tiles per expert (8192/256)

typedef __bf16 bf16x8 __attribute__((ext_vector_type(8)));
typedef float f32x4 __attribute__((ext_vector_type(4)));

__device__ __forceinline__ unsigned short f2bf(float f) {
    union { float f; unsigned u; } v; v.f = f;
    unsigned r = v.u + 0x7fffu + ((v.u >> 16) & 1u);
    return (unsigned short)(r >> 16);
}

// async 16B/lane global->LDS. LDS dest = base + lane*16 (wave-uniform base).
__device__ __forceinline__ void gld16(const unsigned short* g, unsigned short* l) {
    __builtin_amdgcn_global_load_lds(
        (const __attribute__((address_space(1))) unsigned int*)g,
        (__attribute__((address_space(3))) unsigned int*)l, 16, 0, 0);
}

// meta layout (ints): [0..7] count, [8..15] cursor, [16..23] aligned, [24..32] off[9], [33] total
__global__ __launch_bounds__(256) void k_router(const float* __restrict__ x,
                                                const float* __restrict__ Wr,
                                                int* __restrict__ meta,
                                                int* __restrict__ tg_idx,
                                                float* __restrict__ tg_gate) {
    int wave = threadIdx.x >> 6, lane = threadIdx.x & 63;
    int t = blockIdx.x * 4 + wave;
    double acc[NE];
#pragma unroll
    for (int e = 0; e < NE; e++) acc[e] = 0.0;
    const float* xr = x + (size_t)t * DMODEL;
#pragma unroll 4
    for (int j = 0; j < 16; j++) {
        int k = j * 64 + lane;
        double xv = (double)xr[k];
        const float4* wr = (const float4*)(Wr + k * NE);
        float4 w0 = wr[0], w1 = wr[1];
        acc[0] += xv * (double)w0.x; acc[1] += xv * (double)w0.y;
        acc[2] += xv * (double)w0.z; acc[3] += xv * (double)w0.w;
        acc[4] += xv * (double)w1.x; acc[5] += xv * (double)w1.y;
        acc[6] += xv * (double)w1.z; acc[7] += xv * (double)w1.w;
    }
#pragma unroll
    for (int off = 32; off; off >>= 1)
#pragma unroll
        for (int e = 0; e < NE; e++) acc[e] += __shfl_xor(acc[e], off);
    if (lane == 0) {
        double v1 = -1e300, v2 = -1e300; int i1 = 0, i2 = 0;
#pragma unroll
        for (int e = 0; e < NE; e++) {
            double v = acc[e];
            if (v > v1) { v2 = v1; i2 = i1; v1 = v; i1 = e; }
            else if (v > v2) { v2 = v; i2 = e; }
        }
        double g1 = 1.0 / (1.0 + exp(v2 - v1));
        tg_idx[t * 2] = i1; tg_idx[t * 2 + 1] = i2;
        tg_gate[t * 2] = (float)g1; tg_gate[t * 2 + 1] = (float)(1.0 - g1);
        atomicAdd(&meta[i1], 1);
        atomicAdd(&meta[i2], 1);
    }
}

__global__ void k_scan(int* __restrict__ meta) {
    if (threadIdx.x == 0) {
        int acc = 0;
        for (int e = 0; e < NE; e++) {
            int a = (meta[e] + 255) & ~255;
            meta[16 + e] = a;
            meta[24 + e] = acc;
            acc += a;
        }
        meta[24 + NE] = acc;
        meta[33] = acc;
    }
}

__global__ __launch_bounds__(256) void k_build(const int* __restrict__ tg_idx,
                                               const float* __restrict__ tg_gate,
                                               int* __restrict__ meta,
                                               int* __restrict__ tos,
                                               float* __restrict__ gos,
                                               int* __restrict__ sot) {
    int t = blockIdx.x * 256 + threadIdx.x;
#pragma unroll
    for (int kk = 0; kk < 2; kk++) {
        int e = tg_idx[t * 2 + kk];
        int pos = atomicAdd(&meta[8 + e], 1);
        int slot = meta[24 + e] + pos;
        tos[slot] = t;
        gos[slot] = tg_gate[t * 2 + kk];
        sot[t * 2 + kk] = slot;
    }
}

__global__ __launch_bounds__(256) void k_gather(const float* __restrict__ x,
                                                const int* __restrict__ tos,
                                                const int* __restrict__ meta,
                                                unsigned short* __restrict__ xg) {
    int s = blockIdx.x;
    if (s >= meta[33]) return;
    int t = tos[s];
    int tid = threadIdx.x;
#pragma unroll
    for (int j = 0; j < 4; j++) {
        int k = tid + j * 256;
        float v = (t >= 0) ? x[(size_t)t * DMODEL + k] : 0.f;
        xg[(size_t)s * DMODEL + k] = f2bf(v);
    }
}

// in: [E][R][C] fp32 -> out: [E][C][R] bf16.
__global__ __launch_bounds__(256) void k_transpose(const float* __restrict__ in,
                                                   unsigned short* __restrict__ out,
                                                   int R, int C) {
    int e = blockIdx.z;
    const float* src = in + (size_t)e * R * C;
    unsigned short* dst = out + (size_t)e * R * C;
    int g = threadIdx.x >> 3, l8 = threadIdx.x & 7;
    int rb = blockIdx.y * 64 + l8 * 8;       // 8 rows per thread
    int cb = blockIdx.x * 128 + g * 4;       // 4 cols per thread
    f32x4 v[8];
#pragma unroll
    for (int i = 0; i < 8; i++)
        v[i] = *(const f32x4*)&src[(size_t)(rb + i) * C + cb];
#pragma unroll
    for (int j = 0; j < 4; j++) {
        unsigned short o[8];
#pragma unroll
        for (int i = 0; i < 8; i++) o[i] = f2bf(v[i][j]);
        *(uint4*)&dst[(size_t)(cb + j) * R + rb] = *(uint4*)o;
    }
}

// MODE 1: h = relu(xg @ W1t[e] + b1[e]) -> bf16 H.
// MODE 2: y[split][slot] = h @ W2t[e]   (split-K=2, bias+gate in combine)
//
// BM=256 x BN=128, 512 threads (8 waves, 4Mx2N, 64x64/wave). K-loop in
// K=32-half phases: per phase 8x ds_read_b128 + 3x global_load_lds (unit
// phi+3) + vmcnt(6) + barrier + 16 MFMA (setprio) + barrier. 4 rotating LDS
// regions per operand (dbuf x khalf), prefetch depth 3 phases, steady-state
// vmcnt never drains to 0 (T3+T4), drains 3->0 only in last 3 phases.
// LDS rows are 64B (32 bf16): fragment reads cover full rows across the 4
// k-chunk lanes -> bank-balanced without swizzle; gld16 source stays linear.
// 1D grid, strip-major XCD-pinned: xcd = L&7; all mtiles of one weight strip
// (fixed e,nt[,kq]) run on one XCD so the 256-512 KB B-strip stays in its L2.
template <int MODE>
__global__ __launch_bounds__(512, 2) void k_gemm(const unsigned short* __restrict__ A,
                                                 const unsigned short* __restrict__ Bt,
                                                 const float* __restrict__ bias,
                                                 const int* __restrict__ meta,
                                                 unsigned short* __restrict__ H,
                                                 float* __restrict__ Y) {
    constexpr int KFULL = (MODE == 1) ? DMODEL : DFF;
    constexpr int K     = (MODE == 1) ? DMODEL : DFF / 2;  // MODE2: split-K half
    constexpr int N     = (MODE == 1) ? DFF : DMODEL;
    constexpr int NPH   = K / 32;                          // K-half phases

    int L = blockIdx.x;
    int xcd = L & 7, c = L >> 3;
    int sgrp = c >> 5, mt = c & 31;          // MT_CAP = 32
    int s = (sgrp << 3) | xcd;
    int e, kq, nt;
    if constexpr (MODE == 1) { e = s >> 5; nt = s & 31; kq = 0; }
    else                     { e = s >> 4; kq = (s >> 3) & 1; nt = s & 7; }
    if (mt * 256 >= meta[16 + e]) return;
    int row0 = meta[24 + e] + mt * 256;
    int col0 = nt * 128;
    const unsigned short* Ae = A + (size_t)row0 * KFULL + kq * K;
    const unsigned short* Be = Bt + (size_t)e * N * KFULL + (size_t)col0 * KFULL + kq * K;
    const float* be = bias + (size_t)e * N;

    // 4 rotating regions per operand: [dbuf][khalf][rows][32 k]
    __shared__ __align__(16) unsigned short As[2][2][256 * 32];  // 64 KiB
    __shared__ __align__(16) unsigned short Bs[2][2][128 * 32];  // 32 KiB

    int tid = threadIdx.x;
    int lane = tid & 63, wv = tid >> 6;      // 8 waves
    int wm = wv >> 1, wn = wv & 1;           // 4M x 2N wave grid
    int q = lane >> 4, r16 = lane & 15;
    int srow = lane >> 2, scol = lane & 3;   // stage: 16 rows x 4 chunks / instr

    // stage unit u (K-half index): A rows [wv*32, wv*32+32), B rows [wv*16, +16)
    auto stage = [&](int u) {
        int p = (u >> 1) & 1, kh = u & 1;
        const unsigned short* ga = Ae + (size_t)(wv * 32 + srow) * KFULL + u * 32 + scol * 8;
        gld16(ga,                      &As[p][kh][(wv * 32) * 32]);
        gld16(ga + (size_t)16 * KFULL, &As[p][kh][(wv * 32 + 16) * 32]);
        const unsigned short* gb = Be + (size_t)(wv * 16 + srow) * KFULL + u * 32 + scol * 8;
        gld16(gb,                      &Bs[p][kh][(wv * 16) * 32]);
    };

    f32x4 acc[4][4];
#pragma unroll
    for (int i = 0; i < 4; i++)
#pragma unroll
        for (int j = 0; j < 4; j++) acc[i][j] = (f32x4){0.f, 0.f, 0.f, 0.f};

    // prologue: 3 units in flight, publish U0
    stage(0); stage(1); stage(2);
    asm volatile("s_waitcnt vmcnt(6)" ::: "memory");
    __builtin_amdgcn_s_barrier();

#pragma unroll 4
    for (int ph = 0; ph < NPH; ph++) {
        int p = (ph >> 1) & 1, kh = ph & 1;
        const unsigned short* Ar = &As[p][kh][0];
        const unsigned short* Br = &Bs[p][kh][0];
        bf16x8 af[4], bfr[4];
#pragma unroll
        for (int i = 0; i < 4; i++)
            af[i] = *(const bf16x8*)&Ar[(wm * 64 + i * 16 + r16) * 32 + q * 8];
#pragma unroll
        for (int j = 0; j < 4; j++)
            bfr[j] = *(const bf16x8*)&Br[(wn * 64 + j * 16 + r16) * 32 + q * 8];

        if (ph + 3 < NPH) stage(ph + 3);     // region freed after phase ph-1

        // publish U(ph+1) wave-locally; barrier makes it block-visible.
        if (ph < NPH - 3)       asm volatile("s_waitcnt vmcnt(6)" ::: "memory");
        else if (ph == NPH - 3) asm volatile("s_waitcnt vmcnt(3)" ::: "memory");
        else                    asm volatile("s_waitcnt vmcnt(0)" ::: "memory");
        __builtin_amdgcn_s_barrier();

        asm volatile("s_waitcnt lgkmcnt(0)" ::: "memory");
        __builtin_amdgcn_sched_barrier(0);
        __builtin_amdgcn_s_setprio(1);
#pragma unroll
        for (int i = 0; i < 4; i++)
#pragma unroll
            for (int j = 0; j < 4; j++)
                acc[i][j] = __builtin_amdgcn_mfma_f32_16x16x32_bf16(af[i], bfr[j], acc[i][j], 0, 0, 0);
        __builtin_amdgcn_s_setprio(0);
        __builtin_amdgcn_sched_barrier(0);
        __builtin_amdgcn_s_barrier();        // all reads of this region done
    }

    if constexpr (MODE == 1) {
#pragma unroll
        for (int i = 0; i < 4; i++) {
#pragma unroll
            for (int rr = 0; rr < 4; rr++) {
                int gs = row0 + wm * 64 + i * 16 + q * 4 + rr;
#pragma unroll
                for (int j = 0; j < 4; j++) {
                    int gn = col0 + wn * 64 + j * 16 + r16;
                    float v = acc[i][j][rr] + be[gn];
                    H[(size_t)gs * DFF + gn] = f2bf(v > 0.f ? v : 0.f);
                }
            }
        }
    } else {
        float* Yp = Y + (size_t)kq * CAP * DMODEL;
#pragma unroll
        for (int i = 0; i < 4; i++) {
#pragma unroll
            for (int rr = 0; rr < 4; rr++) {
                int gs = row0 + wm * 64 + i * 16 + q * 4 + rr;
#pragma unroll
                for (int j = 0; j < 4; j++) {
                    int gn = col0 + wn * 64 + j * 16 + r16;
                    Yp[(size_t)gs * DMODEL + gn] = acc[i][j][rr];
                }
            }
        }
    }
}

// out[t] = g0*(y0[s0]+y1[s0]+b2[e0]) + g1*(y0[s1]+y1[s1]+b2[e1])
__global__ __launch_bounds__(256) void k_combine(const float* __restrict__ Y,
                                                 const int* __restrict__ tg_idx,
                                                 const float* __restrict__ tg_gate,
                                                 const int* __restrict__ sot,
                                                 const float* __restrict__ b2,
                                                 float* __restrict__ out) {
    int t = blockIdx.x;
    int e0 = tg_idx[t * 2], e1 = tg_idx[t * 2 + 1];
    float g0 = tg_gate[t * 2], g1 = tg_gate[t * 2 + 1];
    int s0 = sot[t * 2], s1 = sot[t * 2 + 1];
    const float* y0 = Y;
    const float* y1 = Y + (size_t)CAP * DMODEL;
    int d = threadIdx.x * 4;
    f32x4 a0 = *(const f32x4*)&y0[(size_t)s0 * DMODEL + d];
    f32x4 b0 = *(const f32x4*)&y1[(size_t)s0 * DMODEL + d];
    f32x4 a1 = *(const f32x4*)&y0[(size_t)s1 * DMODEL + d];
    f32x4 b1v = *(const f32x4*)&y1[(size_t)s1 * DMODEL + d];
    f32x4 c0 = *(const f32x4*)&b2[(size_t)e0 * DMODEL + d];
    f32x4 c1 = *(const f32x4*)&b2[(size_t)e1 * DMODEL + d];
    f32x4 r;
#pragma unroll
    for (int i = 0; i < 4; i++)
        r[i] = g0 * (a0[i] + b0[i] + c0[i]) + g1 * (a1[i] + b1v[i] + c1[i]);
    *(f32x4*)&out[(size_t)t * DMODEL + d] = r;
}

extern "C" void kernel_launch(void* const* d_in, const int* in_sizes, int n_in,
                              void* d_out, int out_size, void* d_ws, size_t ws_size,
                              hipStream_t stream) {
    const float* x  = (const float*)d_in[0];
    const float* Wr = (const float*)d_in[1];
    const float* W1 = (const float*)d_in[2];
    const float* b1 = (const float*)d_in[3];
    const float* W2 = (const float*)d_in[4];
    const float* b2 = (const float*)d_in[5];
    float* out = (float*)d_out;

    char* p = (char*)d_ws;
    auto alloc = [&](size_t bytes) {
        char* q = p;
        p += (bytes + 255) & ~(size_t)255;
        return q;
    };
    int*   meta    = (int*)alloc(64 * 4);
    int*   tg_idx  = (int*)alloc((size_t)T_TOK * 2 * 4);
    float* tg_gate = (float*)alloc((size_t)T_TOK * 2 * 4);
    int*   tos     = (int*)alloc((size_t)CAP * 4);
    float* gos     = (float*)alloc((size_t)CAP * 4);
    int*   sot     = (int*)alloc((size_t)T_TOK * 2 * 4);
    unsigned short* xg  = (unsigned short*)alloc((size_t)CAP * DMODEL * 2);
    unsigned short* W1t = (unsigned short*)alloc((size_t)NE * DMODEL * DFF * 2);
    unsigned short* W2t = (unsigned short*)alloc((size_t)NE * DMODEL * DFF * 2);
    unsigned short* h   = (unsigned short*)alloc((size_t)CAP * DFF * 2);
    // y (2 x CAP x DMODEL fp32 = 83.9 MB) aliases xg+W1t (88 MB): both are dead
    // by the time GEMM2 writes y (GEMM2 reads only h, W2t, meta).
    float* y = (float*)xg;

    hipMemsetAsync(meta, 0, 64 * 4, stream);
    hipMemsetAsync(tos, 0xFF, (size_t)CAP * 4, stream);  // pad slots -> t=-1

    k_router<<<T_TOK / 4, 256, 0, stream>>>(x, Wr, meta, tg_idx, tg_gate);
    k_scan<<<1, 64, 0, stream>>>(meta);
    k_build<<<T_TOK / 256, 256, 0, stream>>>(tg_idx, tg_gate, meta, tos, gos, sot);
    k_gather<<<CAP, 256, 0, stream>>>(x, tos, meta, xg);
    // W1 transpose right before GEMM1, W2 transpose after it: each GEMM runs
    // against an L3 still warm with its own (bf16) weights.
    k_transpose<<<dim3(DFF / 128, DMODEL / 64, NE), 256, 0, stream>>>(W1, W1t, DMODEL, DFF);
    k_gemm<1><<<dim3(NE * 32 * MT_CAP), 512, 0, stream>>>(xg, W1t, b1, meta, h, nullptr);
    k_transpose<<<dim3(DMODEL / 128, DFF / 64, NE), 256, 0, stream>>>(W2, W2t, DFF, DMODEL);
    k_gemm<2><<<dim3(NE * 2 * 8 * MT_CAP), 512, 0, stream>>>(h, W2t, b2, meta, nullptr, y);
    k_combine<<<T_TOK, 256, 0, stream>>>(y, tg_idx, tg_gate, sot, b2, out);
}

// Round 2
// 709.629 us; speedup vs baseline: 1.1016x; 1.1016x over previous
//
#include <hip/hip_runtime.h>

// MoE top-2, D=1024, DFF=4096, E=8, T=4096. Sparse grouped-GEMM, bf16 MFMA.
// GEMM: 256x256 tile, BK=64, 8 waves (2M x 4N), per-wave 128x64 (8x4 frags ->
// LDS-read <= MFMA rate). Conflict-free granule-XOR LDS (proven in round-0),
// counted-vmcnt staggered staging (never drains to 0 in steady state),
// 2 barriers per K-tile, setprio around MFMA clusters, XCD strip pinning.

#define T_TOK 4096
#define DMODEL 1024
#define DFF 4096
#define NE 8
#define CAP 10240           // max aligned slots: 8192 + 8*255 -> 10232, padded
#define MT_CAP 32           // max 256-row m-tiles per expert (8192/256)

typedef __bf16 bf16x8 __attribute__((ext_vector_type(8)));
typedef float f32x4 __attribute__((ext_vector_type(4)));

#define VMW(n) asm volatile("s_waitcnt vmcnt(" #n ")" ::: "memory")
#define BARRIER() do { asm volatile("" ::: "memory"); __builtin_amdgcn_s_barrier(); asm volatile("" ::: "memory"); } while (0)

__device__ __forceinline__ unsigned short f2bf(float f) {
    union { float f; unsigned u; } v; v.f = f;
    unsigned r = v.u + 0x7fffu + ((v.u >> 16) & 1u);
    return (unsigned short)(r >> 16);
}

// async 16B/lane global->LDS. LDS dest = base + lane*16 (wave-uniform base).
__device__ __forceinline__ void gld16(const unsigned short* g, unsigned short* l) {
    __builtin_amdgcn_global_load_lds(
        (const __attribute__((address_space(1))) unsigned int*)g,
        (__attribute__((address_space(3))) unsigned int*)l, 16, 0, 0);
}

// meta layout (ints): [0..7] count, [8..15] cursor, [16..23] aligned, [24..32] off[9], [33] total
__global__ __launch_bounds__(256) void k_router(const float* __restrict__ x,
                                                const float* __restrict__ Wr,
                                                int* __restrict__ meta,
                                                int* __restrict__ tg_idx,
                                                float* __restrict__ tg_gate) {
    int wave = threadIdx.x >> 6, lane = threadIdx.x & 63;
    int t = blockIdx.x * 4 + wave;
    double acc[NE];
#pragma unroll
    for (int e = 0; e < NE; e++) acc[e] = 0.0;
    const float* xr = x + (size_t)t * DMODEL;
#pragma unroll 4
    for (int j = 0; j < 16; j++) {
        int k = j * 64 + lane;
        double xv = (double)xr[k];
        const float4* wr = (const float4*)(Wr + k * NE);
        float4 w0 = wr[0], w1 = wr[1];
        acc[0] += xv * (double)w0.x; acc[1] += xv * (double)w0.y;
        acc[2] += xv * (double)w0.z; acc[3] += xv * (double)w0.w;
        acc[4] += xv * (double)w1.x; acc[5] += xv * (double)w1.y;
        acc[6] += xv * (double)w1.z; acc[7] += xv * (double)w1.w;
    }
#pragma unroll
    for (int off = 32; off; off >>= 1)
#pragma unroll
        for (int e = 0; e < NE; e++) acc[e] += __shfl_xor(acc[e], off);
    if (lane == 0) {
        double v1 = -1e300, v2 = -1e300; int i1 = 0, i2 = 0;
#pragma unroll
        for (int e = 0; e < NE; e++) {
            double v = acc[e];
            if (v > v1) { v2 = v1; i2 = i1; v1 = v; i1 = e; }
            else if (v > v2) { v2 = v; i2 = e; }
        }
        double g1 = 1.0 / (1.0 + exp(v2 - v1));
        tg_idx[t * 2] = i1; tg_idx[t * 2 + 1] = i2;
        tg_gate[t * 2] = (float)g1; tg_gate[t * 2 + 1] = (float)(1.0 - g1);
        atomicAdd(&meta[i1], 1);
        atomicAdd(&meta[i2], 1);
    }
}

__global__ void k_scan(int* __restrict__ meta) {
    if (threadIdx.x == 0) {
        int acc = 0;
        for (int e = 0; e < NE; e++) {
            int a = (meta[e] + 255) & ~255;
            meta[16 + e] = a;
            meta[24 + e] = acc;
            acc += a;
        }
        meta[24 + NE] = acc;
        meta[33] = acc;
    }
}

__global__ __launch_bounds__(256) void k_build(const int* __restrict__ tg_idx,
                                               const float* __restrict__ tg_gate,
                                               int* __restrict__ meta,
                                               int* __restrict__ tos,
                                               float* __restrict__ gos,
                                               int* __restrict__ sot) {
    int t = blockIdx.x * 256 + threadIdx.x;
#pragma unroll
    for (int kk = 0; kk < 2; kk++) {
        int e = tg_idx[t * 2 + kk];
        int pos = atomicAdd(&meta[8 + e], 1);
        int slot = meta[24 + e] + pos;
        tos[slot] = t;
        gos[slot] = tg_gate[t * 2 + kk];
        sot[t * 2 + kk] = slot;
    }
}

__global__ __launch_bounds__(256) void k_gather(const float* __restrict__ x,
                                                const int* __restrict__ tos,
                                                const int* __restrict__ meta,
                                                unsigned short* __restrict__ xg) {
    int s = blockIdx.x;
    if (s >= meta[33]) return;
    int t = tos[s];
    int tid = threadIdx.x;
#pragma unroll
    for (int j = 0; j < 4; j++) {
        int k = tid + j * 256;
        float v = (t >= 0) ? x[(size_t)t * DMODEL + k] : 0.f;
        xg[(size_t)s * DMODEL + k] = f2bf(v);
    }
}

// Both weight transposes in one launch. id<4096: W1 (R=1024,C=4096);
// else W2 (R=4096,C=1024). in [E][R][C] f32 -> out [E][C][R] bf16.
__global__ __launch_bounds__(256) void k_transpose2(const float* __restrict__ W1,
                                                    unsigned short* __restrict__ W1t,
                                                    const float* __restrict__ W2,
                                                    unsigned short* __restrict__ W2t) {
    int id = blockIdx.x;
    const float* in; unsigned short* out; int R, C, rem;
    if (id < 4096) { in = W1; out = W1t; R = DMODEL; C = DFF; rem = id; }
    else           { in = W2; out = W2t; R = DFF; C = DMODEL; rem = id - 4096; }
    int e = rem >> 9, r2 = rem & 511;
    int nbx = C >> 7;
    int bx = r2 % nbx, by = r2 / nbx;
    const float* src = in + (size_t)e * R * C;
    unsigned short* dst = out + (size_t)e * R * C;
    int g = threadIdx.x >> 3, l8 = threadIdx.x & 7;
    int rb = by * 64 + l8 * 8;
    int cb = bx * 128 + g * 4;
    f32x4 v[8];
#pragma unroll
    for (int i = 0; i < 8; i++)
        v[i] = *(const f32x4*)&src[(size_t)(rb + i) * C + cb];
#pragma unroll
    for (int j = 0; j < 4; j++) {
        unsigned short o[8];
#pragma unroll
        for (int i = 0; i < 8; i++) o[i] = f2bf(v[i][j]);
        *(uint4*)&dst[(size_t)(cb + j) * R + rb] = *(uint4*)o;
    }
}

// MODE 1: h = relu(xg @ W1t[e] + b1[e]) -> bf16 H.
// MODE 2: y[kq][slot] = h(kq half) @ W2t[e]  (split-K=2; bias+gate in combine)
template <int MODE>
__global__ __launch_bounds__(512, 2) void k_gemm(const unsigned short* __restrict__ A,
                                                 const unsigned short* __restrict__ Bt,
                                                 const float* __restrict__ bias,
                                                 const int* __restrict__ meta,
                                                 unsigned short* __restrict__ H,
                                                 float* __restrict__ Y) {
    constexpr int KFULL = (MODE == 1) ? DMODEL : DFF;
    constexpr int K     = (MODE == 1) ? DMODEL : DFF / 2;
    constexpr int N     = (MODE == 1) ? DFF : DMODEL;
    constexpr int NT    = K / 64;                     // K-tiles

    int L = blockIdx.x;
    int xcd = L & 7, c = L >> 3;
    int mt = c & 31, sgrp = c >> 5;
    int s = (sgrp << 3) | xcd;
    int e, kq, nt;
    if constexpr (MODE == 1) { e = s >> 4; nt = s & 15; kq = 0; }
    else                     { e = s >> 3; kq = (s >> 2) & 1; nt = s & 3; }
    if (mt * 256 >= meta[16 + e]) return;
    int row0 = meta[24 + e] + mt * 256;
    int col0 = nt * 256;
    const unsigned short* Ae = A + (size_t)row0 * KFULL + kq * K;
    const unsigned short* Be = Bt + (size_t)e * N * KFULL + (size_t)col0 * KFULL + kq * K;
    const float* be = bias + (size_t)e * N;

    // [buf][256 rows][64 k] bf16, rows = 128B = exactly 32 banks.
    // Slot g of row r holds global k-granule g^(r&7): quarter-wave frag reads
    // spread over all 8 granule slots -> 2 lanes/bank-quad = free.
    __shared__ __align__(16) unsigned short As[2][256 * 64];  // 64 KiB
    __shared__ __align__(16) unsigned short Bs[2][256 * 64];  // 64 KiB

    int tid = threadIdx.x;
    int lane = tid & 63, wv = tid >> 6;      // 8 waves
    int wm = wv >> 2, wn = wv & 3;           // 2M x 4N wave grid, per-wave 128x64
    int q = lane >> 4, r16 = lane & 15;
    int sw = r16 & 7;
    int rl = lane >> 3, gsl = lane & 7;
    int skoff = (gsl ^ rl) << 3;             // pre-swizzled k-short offset

    // one call = 64 rows (8 rows/wave), 1 gld16/thread
    auto stageA = [&](int bn, int cc, int tn) {
        gld16(Ae + (size_t)(cc * 64 + wv * 8 + rl) * KFULL + tn * 64 + skoff,
              &As[bn][(cc * 64 + wv * 8) * 64]);
    };
    auto stageB = [&](int bn, int cc, int tn) {
        gld16(Be + (size_t)(cc * 64 + wv * 8 + rl) * KFULL + tn * 64 + skoff,
              &Bs[bn][(cc * 64 + wv * 8) * 64]);
    };

    f32x4 acc[8][4];
#pragma unroll
    for (int i = 0; i < 8; i++)
#pragma unroll
        for (int j = 0; j < 4; j++) acc[i][j] = (f32x4){0.f, 0.f, 0.f, 0.f};

    // prologue: tile 0 in steady-state order (B0,B1 | Ac1 | Ac2)
    stageB(0, 0, 0); stageB(0, 1, 0);
    stageB(0, 2, 0); stageB(0, 3, 0);
    stageA(0, 0, 0); stageA(0, 2, 0);   // A rows 0..63 / 128..191
    stageA(0, 1, 0); stageA(0, 3, 0);   // A rows 64..127 / 192..255
    VMW(2);
    BARRIER();

#define PH_READ_A(I0)                                                                    \
    af[0][0] = *(const bf16x8*)&Ab[(wm * 128 + (I0) * 16 + r16) * 64 + ((q ^ sw) << 3)];         \
    af[0][1] = *(const bf16x8*)&Ab[(wm * 128 + (I0) * 16 + r16) * 64 + (((4 + q) ^ sw) << 3)];   \
    af[1][0] = *(const bf16x8*)&Ab[(wm * 128 + (I0 + 1) * 16 + r16) * 64 + ((q ^ sw) << 3)];     \
    af[1][1] = *(const bf16x8*)&Ab[(wm * 128 + (I0 + 1) * 16 + r16) * 64 + (((4 + q) ^ sw) << 3)];

#define PH_MFMA(I0)                                                                                   \
    __builtin_amdgcn_s_setprio(1);                                                                    \
    _Pragma("unroll") for (int j = 0; j < 4; j++) {                                                   \
        acc[I0][j]     = __builtin_amdgcn_mfma_f32_16x16x32_bf16(af[0][0], bfr[j][0], acc[I0][j], 0, 0, 0);     \
        acc[I0][j]     = __builtin_amdgcn_mfma_f32_16x16x32_bf16(af[0][1], bfr[j][1], acc[I0][j], 0, 0, 0);     \
        acc[I0 + 1][j] = __builtin_amdgcn_mfma_f32_16x16x32_bf16(af[1][0], bfr[j][0], acc[I0 + 1][j], 0, 0, 0); \
        acc[I0 + 1][j] = __builtin_amdgcn_mfma_f32_16x16x32_bf16(af[1][1], bfr[j][1], acc[I0 + 1][j], 0, 0, 0); \
    }                                                                                                 \
    __builtin_amdgcn_s_setprio(0);

#pragma unroll 2
    for (int t = 0; t < NT; ++t) {
        const int b = t & 1, bn = b ^ 1;
        const bool pf = (t + 1 < NT);
        const unsigned short* Ab = &As[b][0];
        const unsigned short* Bb = &Bs[b][0];
        bf16x8 bfr[4][2], af[2][2];
        // B frags for the whole tile (held in regs)
#pragma unroll
        for (int j = 0; j < 4; j++) {
            bfr[j][0] = *(const bf16x8*)&Bb[(wn * 64 + j * 16 + r16) * 64 + ((q ^ sw) << 3)];
            bfr[j][1] = *(const bf16x8*)&Bb[(wn * 64 + j * 16 + r16) * 64 + (((4 + q) ^ sw) << 3)];
        }
        // PH0: i=0,1 ; stage B half0 of t+1
        PH_READ_A(0)
        if (pf) { stageB(bn, 0, t + 1); stageB(bn, 1, t + 1); }
        PH_MFMA(0)
        // PH1: i=2,3 ; stage B half1 of t+1
        PH_READ_A(2)
        if (pf) { stageB(bn, 2, t + 1); stageB(bn, 3, t + 1); }
        PH_MFMA(2)
        // mid wait: this tile's A rows 64..127/192..255 (staged last tile, 2 oldest
        // outstanding). pf: leave t+1's 4 B-loads in flight.
        if (pf) { VMW(4); } else { VMW(0); }
        BARRIER();
        // PH2: i=4,5 ; stage A first-64-rows of both halves of t+1
        PH_READ_A(4)
        if (pf) { stageA(bn, 0, t + 1); stageA(bn, 2, t + 1); }
        PH_MFMA(4)
        // PH3: i=6,7 ; stage A last-64-rows of both halves of t+1
        PH_READ_A(6)
        if (pf) { stageA(bn, 1, t + 1); stageA(bn, 3, t + 1); }
        PH_MFMA(6)
        // boundary: need t+1's B + A-first (6 oldest of its 8); leave A-last (2).
        if (pf) { VMW(2); BARRIER(); }
    }
#undef PH_READ_A
#undef PH_MFMA

    if constexpr (MODE == 1) {
        float bj[4];
#pragma unroll
        for (int j = 0; j < 4; j++) bj[j] = be[col0 + wn * 64 + j * 16 + r16];
#pragma unroll
        for (int i = 0; i < 8; i++) {
#pragma unroll
            for (int rr = 0; rr < 4; rr++) {
                int gs = row0 + wm * 128 + i * 16 + q * 4 + rr;
#pragma unroll
                for (int j = 0; j < 4; j++) {
                    int gn = col0 + wn * 64 + j * 16 + r16;
                    float v = acc[i][j][rr] + bj[j];
                    H[(size_t)gs * DFF + gn] = f2bf(v > 0.f ? v : 0.f);
                }
            }
        }
    } else {
        float* Yp = Y + (size_t)kq * CAP * DMODEL;
#pragma unroll
        for (int i = 0; i < 8; i++) {
#pragma unroll
            for (int rr = 0; rr < 4; rr++) {
                int gs = row0 + wm * 128 + i * 16 + q * 4 + rr;
#pragma unroll
                for (int j = 0; j < 4; j++) {
                    int gn = col0 + wn * 64 + j * 16 + r16;
                    Yp[(size_t)gs * DMODEL + gn] = acc[i][j][rr];
                }
            }
        }
    }
}

// out[t] = g0*(y0[s0]+y1[s0]+b2[e0]) + g1*(y0[s1]+y1[s1]+b2[e1])
__global__ __launch_bounds__(256) void k_combine(const float* __restrict__ Y,
                                                 const int* __restrict__ tg_idx,
                                                 const float* __restrict__ tg_gate,
                                                 const int* __restrict__ sot,
                                                 const float* __restrict__ b2,
                                                 float* __restrict__ out) {
    int t = blockIdx.x;
    int e0 = tg_idx[t * 2], e1 = tg_idx[t * 2 + 1];
    float g0 = tg_gate[t * 2], g1 = tg_gate[t * 2 + 1];
    int s0 = sot[t * 2], s1 = sot[t * 2 + 1];
    const float* y0 = Y;
    const float* y1 = Y + (size_t)CAP * DMODEL;
    int d = threadIdx.x * 4;
    f32x4 a0 = *(const f32x4*)&y0[(size_t)s0 * DMODEL + d];
    f32x4 b0 = *(const f32x4*)&y1[(size_t)s0 * DMODEL + d];
    f32x4 a1 = *(const f32x4*)&y0[(size_t)s1 * DMODEL + d];
    f32x4 b1v = *(const f32x4*)&y1[(size_t)s1 * DMODEL + d];
    f32x4 c0 = *(const f32x4*)&b2[(size_t)e0 * DMODEL + d];
    f32x4 c1 = *(const f32x4*)&b2[(size_t)e1 * DMODEL + d];
    f32x4 r;
#pragma unroll
    for (int i = 0; i < 4; i++)
        r[i] = g0 * (a0[i] + b0[i] + c0[i]) + g1 * (a1[i] + b1v[i] + c1[i]);
    *(f32x4*)&out[(size_t)t * DMODEL + d] = r;
}

extern "C" void kernel_launch(void* const* d_in, const int* in_sizes, int n_in,
                              void* d_out, int out_size, void* d_ws, size_t ws_size,
                              hipStream_t stream) {
    const float* x  = (const float*)d_in[0];
    const float* Wr = (const float*)d_in[1];
    const float* W1 = (const float*)d_in[2];
    const float* b1 = (const float*)d_in[3];
    const float* W2 = (const float*)d_in[4];
    const float* b2 = (const float*)d_in[5];
    float* out = (float*)d_out;

    char* p = (char*)d_ws;
    auto alloc = [&](size_t bytes) {
        char* q = p;
        p += (bytes + 255) & ~(size_t)255;
        return q;
    };
    int*   meta    = (int*)alloc(64 * 4);
    int*   tg_idx  = (int*)alloc((size_t)T_TOK * 2 * 4);
    float* tg_gate = (float*)alloc((size_t)T_TOK * 2 * 4);
    int*   tos     = (int*)alloc((size_t)CAP * 4);
    float* gos     = (float*)alloc((size_t)CAP * 4);
    int*   sot     = (int*)alloc((size_t)T_TOK * 2 * 4);
    unsigned short* xg  = (unsigned short*)alloc((size_t)CAP * DMODEL * 2);
    unsigned short* W1t = (unsigned short*)alloc((size_t)NE * DMODEL * DFF * 2);
    unsigned short* W2t = (unsigned short*)alloc((size_t)NE * DMODEL * DFF * 2);
    unsigned short* h   = (unsigned short*)alloc((size_t)CAP * DFF * 2);
    // y (2 x CAP x DMODEL fp32 = 83.9 MB) aliases xg+W1t (88.1 MB): both dead
    // by the time GEMM2 writes y (GEMM2 reads only h, W2t, meta).
    float* y = (float*)xg;

    hipMemsetAsync(meta, 0, 64 * 4, stream);
    hipMemsetAsync(tos, 0xFF, (size_t)CAP * 4, stream);  // pad slots -> t=-1

    k_router<<<T_TOK / 4, 256, 0, stream>>>(x, Wr, meta, tg_idx, tg_gate);
    k_scan<<<1, 64, 0, stream>>>(meta);
    k_build<<<T_TOK / 256, 256, 0, stream>>>(tg_idx, tg_gate, meta, tos, gos, sot);
    k_gather<<<CAP, 256, 0, stream>>>(x, tos, meta, xg);
    k_transpose2<<<8192, 256, 0, stream>>>(W1, W1t, W2, W2t);
    k_gemm<1><<<dim3(NE * 16 * MT_CAP), 512, 0, stream>>>(xg, W1t, b1, meta, h, nullptr);
    k_gemm<2><<<dim3(NE * 2 * 4 * MT_CAP), 512, 0, stream>>>(h, W2t, b2, meta, nullptr, y);
    k_combine<<<T_TOK, 256, 0, stream>>>(y, tg_idx, tg_gate, sot, b2, out);
}